// Round 6
// baseline (8020.030 us; speedup 1.0000x reference)
//
// LSTM Seq2Seq persistent kernel, round 6: proven L3-coherent (sc0 sc1)
// exchange with per-wave flags; h consumed directly into MFMA fragments.
//
//  - 256 WGs x 256 thr, 1 WG/CU (LDS ~85KB incl. pad). 16 batch groups x 16
//    WGs, canonical roles g=wg&15, jm=wg>>4 (no placement games).
//  - Exchange: data stores (sc0 sc1) -> per-wave s_waitcnt vmcnt(0) ->
//    lane0 flag store (sc0 sc1, slot [g][jm*4+wv]). Consumers: lane l polls
//    flag slot l until >= tag, then one direct data read. Same
//    drain-then-signal ordering rounds 2/3 validated; flags cut poll traffic
//    to 256B/WG/retry (round 4's 32KB re-reads were the regression).
//  - No A LDS buffer: consumers load h(t) straight into A-fragments (two 32B
//    runs per lane) and x(t+1) straight from X (plain cached loads issued a
//    step early). One __syncthreads per encoder step (fm_p); inter-iteration
//    fm_p safety follows from the flag dependency.
//  - Compute: round-4 core (proven): wave wv owns k-tiles {wv,wv+4,wv+8},
//    B-frags f16 hi/lo in VGPRs, fm = Ah*Bh + Ah*Bl + Al*Bh, fm_p reduce,
//    gates elementwise, c in registers. Decoder adds z/LN/relu/y head.

#include <hip/hip_runtime.h>
#include <cmath>

typedef _Float16 f16;
typedef _Float16 f16x8v __attribute__((ext_vector_type(8)));
typedef float f32x4v __attribute__((ext_vector_type(4)));

#define NTHR 256

__device__ __forceinline__ float sigmoidf_(float x) { return 1.0f / (1.0f + expf(-x)); }

__device__ __forceinline__ void st_sc1_f(float* p, float v) {
  asm volatile("global_store_dword %0, %1, off sc0 sc1" :: "v"(p), "v"(v) : "memory");
}
__device__ __forceinline__ void st_sc1_u(unsigned* p, unsigned v) {
  asm volatile("global_store_dword %0, %1, off sc0 sc1" :: "v"(p), "v"(v) : "memory");
}

// lane l polls flag slot l (64 slots) until all >= want.
__device__ __forceinline__ void poll64(const unsigned* base, unsigned want) {
  const unsigned* p = base + (threadIdx.x & 63);
  unsigned guard = 0;
  for (;;) {
    unsigned v;
    asm volatile("global_load_dword %0, %1, off sc0 sc1\n\ts_waitcnt vmcnt(0)"
                 : "=v"(v) : "v"(p) : "memory");
    if (__all((int)(v >= want))) return;
    if (++guard > (1u << 20)) return;   // safety valve (absmax catches corruption)
  }
}

// two 32B coherent runs (p1, p2) -> 4x dwordx4, single drain
__device__ __forceinline__ void ld2x32_sc(const float* p1, const float* p2,
                                          float4& a, float4& b, float4& c, float4& d) {
  asm volatile(
      "global_load_dwordx4 %0, %4, off sc0 sc1\n\t"
      "global_load_dwordx4 %1, %4, off offset:16 sc0 sc1\n\t"
      "global_load_dwordx4 %2, %5, off sc0 sc1\n\t"
      "global_load_dwordx4 %3, %5, off offset:16 sc0 sc1\n\t"
      "s_waitcnt vmcnt(0)"
      : "=&v"(a), "=&v"(b), "=&v"(c), "=&v"(d)
      : "v"(p1), "v"(p2) : "memory");
}

// 64B contiguous coherent load, single drain
__device__ __forceinline__ void ld64_sc(const float* p,
                                        float4& a, float4& b, float4& c, float4& d) {
  asm volatile(
      "global_load_dwordx4 %0, %4, off sc0 sc1\n\t"
      "global_load_dwordx4 %1, %4, off offset:16 sc0 sc1\n\t"
      "global_load_dwordx4 %2, %4, off offset:32 sc0 sc1\n\t"
      "global_load_dwordx4 %3, %4, off offset:48 sc0 sc1\n\t"
      "s_waitcnt vmcnt(0)"
      : "=&v"(a), "=&v"(b), "=&v"(c), "=&v"(d)
      : "v"(p) : "memory");
}

// 8 f32 -> f16 hi + f16 lo fragments
__device__ __forceinline__ void cv8(float4 a, float4 b, f16x8v& h, f16x8v& l) {
  h[0]=(f16)a.x; h[1]=(f16)a.y; h[2]=(f16)a.z; h[3]=(f16)a.w;
  h[4]=(f16)b.x; h[5]=(f16)b.y; h[6]=(f16)b.z; h[7]=(f16)b.w;
  l[0]=(f16)(a.x-(float)h[0]); l[1]=(f16)(a.y-(float)h[1]);
  l[2]=(f16)(a.z-(float)h[2]); l[3]=(f16)(a.w-(float)h[3]);
  l[4]=(f16)(b.x-(float)h[4]); l[5]=(f16)(b.y-(float)h[5]);
  l[6]=(f16)(b.z-(float)h[6]); l[7]=(f16)(b.w-(float)h[7]);
}

__global__ __launch_bounds__(NTHR, 1) void lstm_k(
    const float* __restrict__ X,  const float* __restrict__ Wx,
    const float* __restrict__ Wh, const float* __restrict__ Bg,
    const float* __restrict__ W1, const float* __restrict__ B1,
    const float* __restrict__ LNG, const float* __restrict__ LNB,
    const float* __restrict__ W2, const float* __restrict__ B2,
    float* __restrict__ Y,
    unsigned* __restrict__ SFH, unsigned* __restrict__ SFZ,
    float* __restrict__ HB, float* __restrict__ ZB)
{
  // LDS ~85.5KB (forces 1 WG/CU)
  __shared__ float fm_p[4][64][20];   // per-wave partials [wv][col][row16+pad]
  __shared__ float hst[16][260];      // decoder f32 staging
  __shared__ float w1_lds[16][268];   // W1 slice transposed [col][k]
  __shared__ float w2_lds[8][268];    // W2 slice transposed [col][k]
  __shared__ float lng_lds[256], lnb_lds[256];
  __shared__ float ln_mu[16], ln_rs[16];
  __shared__ float pad_lds[5120];     // occupancy pad: keep LDS > 80KB

  const int tid = threadIdx.x;
  const int wg  = blockIdx.x;
  const int g   = wg & 15;
  const int jm  = wg >> 4;
  const int n0  = g * 16;
  const int k0  = jm * 16;
  unsigned* SFHg = SFH + g * 64;
  unsigned* SFZg = SFZ + g * 64;

  const int l    = tid & 63;
  const int wv   = __builtin_amdgcn_readfirstlane(tid >> 6);
  const int lr   = l & 15;            // A-frag row / B-frag col
  const int ko   = (l >> 4) * 8;      // k octet in 32-k tile
  const int srow = tid & 15;          // staging row (varies within quarter-wave)
  const int scb  = tid >> 4;          // staging col block

  // keep pad_lds alive (opaque never-true condition)
  if (__float_as_uint(LNG[0]) == 0x7fbfffffu) {
    pad_lds[tid] = (float)tid;
    Y[0] = pad_lds[(tid + 1) & 255];
  }

  // ---- B fragments in registers: wave wv owns k-tiles {wv, wv+4, wv+8} ----
  f16x8v Bh[3][4], Bl[3][4];
  #pragma unroll
  for (int ki = 0; ki < 3; ++ki) {
    const int kt = wv + 4 * ki;
    #pragma unroll
    for (int n = 0; n < 4; ++n) {
      const int gcol = n * 256 + k0 + lr;
      #pragma unroll
      for (int j = 0; j < 8; ++j) {
        int k = kt * 32 + ko + j;
        float v = (k < 128) ? Wx[k * 1024 + gcol] : Wh[(k - 128) * 1024 + gcol];
        f16 hi = (f16)v;
        Bh[ki][n][j] = hi;
        Bl[ki][n][j] = (f16)(v - (float)hi);
      }
    }
  }

  // ---- head weights / LN params ----
  for (int idx = tid; idx < 256 * 16; idx += NTHR) {
    int k = idx >> 4, cc = idx & 15;
    w1_lds[cc][k] = W1[k * 256 + k0 + cc];
  }
  for (int idx = tid; idx < 256 * 8; idx += NTHR) {
    int k = idx >> 3, cc = idx & 7;
    w2_lds[cc][k] = W2[k * 128 + jm * 8 + cc];
  }
  lng_lds[tid] = LNG[tid];
  lnb_lds[tid] = LNB[tid];

  const int gr = tid >> 4, gk = tid & 15;
  const float bias0 = Bg[      k0 + gk];
  const float bias1 = Bg[256 + k0 + gk];
  const float bias2 = Bg[512 + k0 + gk];
  const float bias3 = Bg[768 + k0 + gk];
  const float b1reg = B1[k0 + gk];
  const float b2reg = (tid < 128) ? B2[jm * 8 + (tid & 7)] : 0.0f;
  float c_reg = 0.0f;

  // ---- fragment registers; prologue: h(-1)=0, x(0) from X ----
  f16x8v axh, axl, ah1, al1, ah2, al2;
  {
    f16x8v z8 = {0, 0, 0, 0, 0, 0, 0, 0};
    ah1 = z8; al1 = z8; ah2 = z8; al2 = z8;
    const float* xp = X + (size_t)(n0 + lr) * 131072 + wv * 32 + ko;
    cv8(*(const float4*)xp, *(const float4*)(xp + 4), axh, axl);
  }

  // ================= ENCODER (t = 0..1023) =================
  for (int t = 0; t < 1024; ++t) {
    // issue x(t+1) loads early (plain cached; consumed at loop tail)
    float4 xa, xb;
    if (t < 1023) {
      const float* xp = X + (size_t)(n0 + lr) * 131072 + (size_t)(t + 1) * 128 + wv * 32 + ko;
      xa = *(const float4*)xp;
      xb = *(const float4*)(xp + 4);
    }

    f32x4v ac0[4], ac1[4], ac2[4];
    #pragma unroll
    for (int n = 0; n < 4; ++n) { ac0[n] = {0,0,0,0}; ac1[n] = {0,0,0,0}; ac2[n] = {0,0,0,0}; }
    #pragma unroll
    for (int n = 0; n < 4; ++n) {
      ac0[n] = __builtin_amdgcn_mfma_f32_16x16x32_f16(axh, Bh[0][n], ac0[n], 0, 0, 0);
      ac1[n] = __builtin_amdgcn_mfma_f32_16x16x32_f16(axh, Bl[0][n], ac1[n], 0, 0, 0);
      ac2[n] = __builtin_amdgcn_mfma_f32_16x16x32_f16(axl, Bh[0][n], ac2[n], 0, 0, 0);
      ac0[n] = __builtin_amdgcn_mfma_f32_16x16x32_f16(ah1, Bh[1][n], ac0[n], 0, 0, 0);
      ac1[n] = __builtin_amdgcn_mfma_f32_16x16x32_f16(ah1, Bl[1][n], ac1[n], 0, 0, 0);
      ac2[n] = __builtin_amdgcn_mfma_f32_16x16x32_f16(al1, Bh[1][n], ac2[n], 0, 0, 0);
      ac0[n] = __builtin_amdgcn_mfma_f32_16x16x32_f16(ah2, Bh[2][n], ac0[n], 0, 0, 0);
      ac1[n] = __builtin_amdgcn_mfma_f32_16x16x32_f16(ah2, Bl[2][n], ac1[n], 0, 0, 0);
      ac2[n] = __builtin_amdgcn_mfma_f32_16x16x32_f16(al2, Bh[2][n], ac2[n], 0, 0, 0);
    }
    #pragma unroll
    for (int n = 0; n < 4; ++n) {
      f32x4v s = ac0[n] + ac1[n] + ac2[n];
      *(f32x4v*)&fm_p[wv][n * 16 + lr][(l >> 4) * 4] = s;
    }
    __syncthreads();

    {  // gates: reduce partials + bias, activations, publish h + per-wave flag
      float fi = bias0, ff = bias1, fo = bias2, fg = bias3;
      #pragma unroll
      for (int ww = 0; ww < 4; ++ww) {
        fi += fm_p[ww][     gk][gr];
        ff += fm_p[ww][16 + gk][gr];
        fo += fm_p[ww][32 + gk][gr];
        fg += fm_p[ww][48 + gk][gr];
      }
      float si = sigmoidf_(fi), sf = sigmoidf_(ff), so = sigmoidf_(fo);
      float tg = tanhf(fg);
      c_reg = c_reg * sf + si * tg;
      float hv = so * tanhf(c_reg);
      st_sc1_f(HB + (size_t)(t & 1) * 65536 + (size_t)(n0 + gr) * 256 + k0 + gk, hv);
      asm volatile("s_waitcnt vmcnt(0)" ::: "memory");   // h (and x) loads/stores drained
      if (l == 0) st_sc1_u(SFHg + jm * 4 + wv, (unsigned)(t + 1));
    }

    // wait for all 16 producers; load h(t) straight into A-fragments
    poll64(SFHg, (unsigned)(t + 1));
    {
      const float* hb = HB + (size_t)(t & 1) * 65536 + (size_t)(n0 + lr) * 256 + wv * 32 + ko;
      float4 h0, h1, h2, h3;
      ld2x32_sc(hb, hb + 128, h0, h1, h2, h3);
      cv8(h0, h1, ah1, al1);
      cv8(h2, h3, ah2, al2);
    }
    if (t < 1023) cv8(xa, xb, axh, axl);
    // no loop-end barrier: fm_p reuse is ordered by the flag dependency
  }

  // ================= DECODER (s = 0..31) =================
  for (int s = 0; s < 32; ++s) {
    const int t = 1024 + s;

    // fm = h @ Wh + b : h-tiles only
    f32x4v ac0[4], ac1[4], ac2[4];
    #pragma unroll
    for (int n = 0; n < 4; ++n) { ac0[n] = {0,0,0,0}; ac1[n] = {0,0,0,0}; ac2[n] = {0,0,0,0}; }
    #pragma unroll
    for (int n = 0; n < 4; ++n) {
      ac0[n] = __builtin_amdgcn_mfma_f32_16x16x32_f16(ah1, Bh[1][n], ac0[n], 0, 0, 0);
      ac1[n] = __builtin_amdgcn_mfma_f32_16x16x32_f16(ah1, Bl[1][n], ac1[n], 0, 0, 0);
      ac2[n] = __builtin_amdgcn_mfma_f32_16x16x32_f16(al1, Bh[1][n], ac2[n], 0, 0, 0);
      ac0[n] = __builtin_amdgcn_mfma_f32_16x16x32_f16(ah2, Bh[2][n], ac0[n], 0, 0, 0);
      ac1[n] = __builtin_amdgcn_mfma_f32_16x16x32_f16(ah2, Bl[2][n], ac1[n], 0, 0, 0);
      ac2[n] = __builtin_amdgcn_mfma_f32_16x16x32_f16(al2, Bh[2][n], ac2[n], 0, 0, 0);
    }
    #pragma unroll
    for (int n = 0; n < 4; ++n) {
      f32x4v sm = ac0[n] + ac1[n] + ac2[n];
      *(f32x4v*)&fm_p[wv][n * 16 + lr][(l >> 4) * 4] = sm;
    }
    __syncthreads();

    {  // RAW gates (reference decoder has no activations on i,f,o,g)
      float fi = bias0, ff = bias1, fo = bias2, fg = bias3;
      #pragma unroll
      for (int ww = 0; ww < 4; ++ww) {
        fi += fm_p[ww][     gk][gr];
        ff += fm_p[ww][16 + gk][gr];
        fo += fm_p[ww][32 + gk][gr];
        fg += fm_p[ww][48 + gk][gr];
      }
      c_reg = c_reg * ff + fi * fg;
      float hv = fo * tanhf(c_reg);
      st_sc1_f(HB + (size_t)(t & 1) * 65536 + (size_t)(n0 + gr) * 256 + k0 + gk, hv);
      asm volatile("s_waitcnt vmcnt(0)" ::: "memory");
      if (l == 0) st_sc1_u(SFHg + jm * 4 + wv, (unsigned)(t + 1));
    }

    poll64(SFHg, (unsigned)(t + 1));
    {  // frag-load h(t) for next fm
      const float* hb = HB + (size_t)(t & 1) * 65536 + (size_t)(n0 + lr) * 256 + wv * 32 + ko;
      float4 h0, h1, h2, h3;
      ld2x32_sc(hb, hb + 128, h0, h1, h2, h3);
      cv8(h0, h1, ah1, al1);
      cv8(h2, h3, ah2, al2);
    }
    {  // slice-load h(t) rows into hst for the z matmul
      float4 v0, v1, v2, v3;
      ld64_sc(HB + (size_t)(t & 1) * 65536 + (size_t)(n0 + srow) * 256 + scb * 16,
              v0, v1, v2, v3);
      *(float4*)&hst[srow][scb * 16]      = v0;
      *(float4*)&hst[srow][scb * 16 + 4]  = v1;
      *(float4*)&hst[srow][scb * 16 + 8]  = v2;
      *(float4*)&hst[srow][scb * 16 + 12] = v3;
    }
    __syncthreads();

    {  // z = h @ W1 + b1, publish + per-wave flag
      float za = b1reg;
      const float* hr = &hst[gr][0];
      const float* wr = &w1_lds[gk][0];
      #pragma unroll 4
      for (int kc = 0; kc < 64; ++kc) {
        float4 h4 = *(const float4*)(hr + kc * 4);
        float4 w4 = *(const float4*)(wr + kc * 4);
        za = fmaf(h4.x, w4.x, fmaf(h4.y, w4.y, fmaf(h4.z, w4.z, fmaf(h4.w, w4.w, za))));
      }
      st_sc1_f(ZB + (size_t)(n0 + gr) * 256 + k0 + gk, za);
      asm volatile("s_waitcnt vmcnt(0)" ::: "memory");
      if (l == 0) st_sc1_u(SFZg + jm * 4 + wv, (unsigned)(s + 1));
    }

    poll64(SFZg, (unsigned)(s + 1));
    {  // slice-load z -> hst (flag dep implies all hst h-reads retired)
      float4 v0, v1, v2, v3;
      ld64_sc(ZB + (size_t)(n0 + srow) * 256 + scb * 16, v0, v1, v2, v3);
      *(float4*)&hst[srow][scb * 16]      = v0;
      *(float4*)&hst[srow][scb * 16 + 4]  = v1;
      *(float4*)&hst[srow][scb * 16 + 8]  = v2;
      *(float4*)&hst[srow][scb * 16 + 12] = v3;
    }
    __syncthreads();

    {  // LayerNorm stats
      const float* zr = &hst[gr][0];
      float s1 = 0.f, s2 = 0.f;
      #pragma unroll
      for (int u = 0; u < 16; ++u) { float v = zr[gk * 16 + u]; s1 += v; s2 += v * v; }
      #pragma unroll
      for (int d = 1; d < 16; d <<= 1) { s1 += __shfl_xor(s1, d); s2 += __shfl_xor(s2, d); }
      float mu = s1 * (1.0f / 256.0f);
      float var = s2 * (1.0f / 256.0f) - mu * mu;
      float rstd = rsqrtf(var + 1e-5f);
      if (gk == 0) { ln_mu[gr] = mu; ln_rs[gr] = rstd; }
    }
    __syncthreads();

    #pragma unroll
    for (int rep = 0; rep < 4; ++rep) {  // normalize + affine + relu in place
      int f = tid + 256 * rep, r = f >> 6, kq = f & 63;
      float mu = ln_mu[r], rs = ln_rs[r];
      float4 v = *(float4*)&hst[r][kq * 4];
      int cb = kq * 4;
      v.x = fmaxf(fmaf((v.x - mu) * rs, lng_lds[cb    ], lnb_lds[cb    ]), 0.f);
      v.y = fmaxf(fmaf((v.y - mu) * rs, lng_lds[cb + 1], lnb_lds[cb + 1]), 0.f);
      v.z = fmaxf(fmaf((v.z - mu) * rs, lng_lds[cb + 2], lnb_lds[cb + 2]), 0.f);
      v.w = fmaxf(fmaf((v.w - mu) * rs, lng_lds[cb + 3], lnb_lds[cb + 3]), 0.f);
      *(float4*)&hst[r][kq * 4] = v;
    }
    __syncthreads();

    if (tid < 128) {  // y = relu(zn) @ W2 + b2
      int r = tid >> 3, yc = tid & 7;
      float ya = b2reg;
      const float* zr = &hst[r][0];
      const float* wr = &w2_lds[yc][0];
      #pragma unroll 4
      for (int kc = 0; kc < 64; ++kc) {
        float4 z4 = *(const float4*)(zr + kc * 4);
        float4 w4 = *(const float4*)(wr + kc * 4);
        ya = fmaf(z4.x, w4.x, fmaf(z4.y, w4.y, fmaf(z4.z, w4.z, fmaf(z4.w, w4.w, ya))));
      }
      Y[(size_t)(n0 + r) * 4096 + (size_t)s * 128 + jm * 8 + yc] = ya;
    }
    __syncthreads();   // protect hst before next iteration's staging
  }
}

extern "C" void kernel_launch(void* const* d_in, const int* in_sizes, int n_in,
                              void* d_out, int out_size, void* d_ws, size_t ws_size,
                              hipStream_t stream) {
  const float* X   = (const float*)d_in[0];
  const float* Wx  = (const float*)d_in[1];
  const float* Wh  = (const float*)d_in[2];
  const float* b   = (const float*)d_in[3];
  const float* W1  = (const float*)d_in[4];
  const float* b1  = (const float*)d_in[5];
  const float* lng = (const float*)d_in[6];
  const float* lnb = (const float*)d_in[7];
  const float* W2  = (const float*)d_in[8];
  const float* b2  = (const float*)d_in[9];
  float* Y = (float*)d_out;

  // ws layout (bytes):
  //  [0,4096)      SFH  h flags [16 groups][64]
  //  [4096,8192)   SFZ  z flags [16 groups][64]
  //  [8192,+512KB) HB   h double buffer [2][256][256] f32
  //  then 256KB    ZB   z buffer [256][256] f32
  unsigned* SFH = (unsigned*)d_ws;
  unsigned* SFZ = (unsigned*)((char*)d_ws + 4096);
  float* HB = (float*)((char*)d_ws + 8192);
  float* ZB = HB + 2 * 65536;
  (void)in_sizes; (void)n_in; (void)out_size; (void)ws_size;

  hipMemsetAsync(d_ws, 0, 8192, stream);   // clear flags each launch
  hipLaunchKernelGGL(lstm_k, dim3(256), dim3(NTHR), 0, stream,
                     X, Wx, Wh, b, W1, b1, lng, lnb, W2, b2, Y,
                     SFH, SFZ, HB, ZB);
}

// Round 7
// 2990.786 us; speedup vs baseline: 2.6816x; 2.6816x over previous
//
// LSTM Seq2Seq persistent kernel, round 7: round-3 proven structure
// (atomic-counter barrier, single poller, coalesced LDS staging) with the
// encoder loop software-pipelined: x-part MFMAs execute during the barrier
// window, h-part after staging.
//
//  - 256 WGs x 256 threads (4 waves), 1 WG/CU. 16 batch groups x 16 WGs.
//  - WG owns 64 fm columns: gcol(c) = (c>>4)*256 + 16*jm + (c&15).
//    Wave w = N-tile (cols w*16..w*16+16) = gate quadrant w.
//  - Weights: per-WG slice (384x64) split v = hi(f16) + lo(f16), stored as
//    MFMA B-fragments in VGPRs (Bh[12], Bl[12] = 96 VGPRs), loaded at setup.
//  - A operand staged in LDS as f16 hi/lo (row stride 392).
//  - fm = Ah*Bh + Ah*Bl + Al*Bh (3 acc chains; 36 MFMAs/wave encoder step).
//  - h exchange: sc0/sc1 stores via L3 + per-group monotonic atomic counter
//    (drain -> sync -> atomic; single-thread poll w/ s_sleep) - proven.
//  - Encoder pipeline per step t: [12 x-MFMAs] -> wait h(t-1) -> burst-stage
//    -> [24 h-MFMAs] -> fm sync -> gates -> publish h(t) -> stage x(t+1)
//    -> arrive. x-part and conversions hide under barrier/store latency.
//  - Decoder: verbatim round 3.

#include <hip/hip_runtime.h>
#include <cmath>

typedef _Float16 f16;
typedef _Float16 f16x4v __attribute__((ext_vector_type(4)));
typedef _Float16 f16x8v __attribute__((ext_vector_type(8)));
typedef float f32x4v __attribute__((ext_vector_type(4)));

#define NTHR 256
#define WPG  16

__device__ __forceinline__ float sigmoidf_(float x) { return 1.0f / (1.0f + expf(-x)); }

__device__ __forceinline__ void store_sc(float* p, float v) {
  asm volatile("global_store_dword %0, %1, off sc0 sc1" :: "v"(p), "v"(v) : "memory");
}

// 4 independent coherent 16B loads (chunks 4KB apart) + single drain.
__device__ __forceinline__ void ld4_sc(const float* p,
                                       float4& a, float4& b, float4& c, float4& d) {
  asm volatile(
      "global_load_dwordx4 %0, %4, off sc0 sc1\n\t"
      "global_load_dwordx4 %1, %5, off sc0 sc1\n\t"
      "global_load_dwordx4 %2, %6, off sc0 sc1\n\t"
      "global_load_dwordx4 %3, %7, off sc0 sc1\n\t"
      "s_waitcnt vmcnt(0)"
      : "=&v"(a), "=&v"(b), "=&v"(c), "=&v"(d)
      : "v"(p), "v"(p + 1024), "v"(p + 2048), "v"(p + 3072)
      : "memory");
}

__device__ __forceinline__ void arrive_bar(unsigned* cg) {
  asm volatile("s_waitcnt vmcnt(0)" ::: "memory");   // drain sc1 stores to L3
  __syncthreads();
  if (threadIdx.x == 0)
    (void)__hip_atomic_fetch_add(cg, 1u, __ATOMIC_RELAXED, __HIP_MEMORY_SCOPE_AGENT);
}

__device__ __forceinline__ void wait_bar(unsigned* cg, unsigned target) {
  if (threadIdx.x == 0) {
    unsigned guard = 0;
    while (__hip_atomic_load(cg, __ATOMIC_RELAXED, __HIP_MEMORY_SCOPE_AGENT) < target) {
      __builtin_amdgcn_s_sleep(1);
      if (++guard > (1u << 22)) break;   // safety valve
    }
  }
  __syncthreads();
}

__device__ __forceinline__ void conv4_wr(float4 v, f16* ph, f16* pl) {
  f16x4v h, l;
  h[0] = (f16)v.x; h[1] = (f16)v.y; h[2] = (f16)v.z; h[3] = (f16)v.w;
  l[0] = (f16)(v.x - (float)h[0]); l[1] = (f16)(v.y - (float)h[1]);
  l[2] = (f16)(v.z - (float)h[2]); l[3] = (f16)(v.w - (float)h[3]);
  *(f16x4v*)ph = h; *(f16x4v*)pl = l;
}

__device__ __forceinline__ void conv8_wr(float4 a, float4 b, f16* ph, f16* pl) {
  f16x8v h, l;
  h[0]=(f16)a.x; h[1]=(f16)a.y; h[2]=(f16)a.z; h[3]=(f16)a.w;
  h[4]=(f16)b.x; h[5]=(f16)b.y; h[6]=(f16)b.z; h[7]=(f16)b.w;
  l[0]=(f16)(a.x-(float)h[0]); l[1]=(f16)(a.y-(float)h[1]);
  l[2]=(f16)(a.z-(float)h[2]); l[3]=(f16)(a.w-(float)h[3]);
  l[4]=(f16)(b.x-(float)h[4]); l[5]=(f16)(b.y-(float)h[5]);
  l[6]=(f16)(b.z-(float)h[6]); l[7]=(f16)(b.w-(float)h[7]);
  *(f16x8v*)ph = h; *(f16x8v*)pl = l;
}

__global__ __launch_bounds__(NTHR, 1) void lstm_k(
    const float* __restrict__ X,  const float* __restrict__ Wx,
    const float* __restrict__ Wh, const float* __restrict__ Bg,
    const float* __restrict__ W1, const float* __restrict__ B1,
    const float* __restrict__ LNG, const float* __restrict__ LNB,
    const float* __restrict__ W2, const float* __restrict__ B2,
    float* __restrict__ Y, unsigned* __restrict__ CNT,
    float* __restrict__ hbuf, float* __restrict__ zbuf)
{
  // LDS total ~74KB
  __shared__ f16   A_hi[16][392];     // A operand hi (row stride 784B)
  __shared__ f16   A_lo[16][392];
  __shared__ float fm_lds[16][65];
  __shared__ float hst[16][260];      // decoder head staging (f32)
  __shared__ float w1_lds[16][268];   // W1 slice transposed [col][k]
  __shared__ float w2_lds[8][268];    // W2 slice transposed [col][k]
  __shared__ float lng_lds[256], lnb_lds[256];
  __shared__ float ln_mu[16], ln_rs[16];

  const int tid = threadIdx.x;
  const int wg  = blockIdx.x;
  const int g   = wg & 15;
  const int jm  = wg >> 4;
  const int n0  = g * 16;
  const int k0  = jm * 16;
  unsigned* cg  = CNT + g * 32;   // 128B-spaced per-group counter

  const int l     = tid & 63;
  const int w     = __builtin_amdgcn_readfirstlane(tid >> 6);  // wave = N-tile
  const int krow0 = (l >> 4) * 8;     // k octet within a 32-k tile
  const int arow  = l & 15;           // A-frag row for this lane

  // ---- B fragments into registers (one-time). Lane l holds
  // B[kt*32 + krow0 + j][w*16 + (l&15)] for j=0..7, split hi/lo f16. ----
  f16x8v Bh[12], Bl[12];
  {
    const int bcol = w * 256 + k0 + (l & 15);   // global fm column
    #pragma unroll
    for (int kt = 0; kt < 12; ++kt) {
      #pragma unroll
      for (int j = 0; j < 8; ++j) {
        int k = kt * 32 + krow0 + j;
        float v = (kt < 4) ? Wx[k * 1024 + bcol] : Wh[(k - 128) * 1024 + bcol];
        f16 hi = (f16)v;
        Bh[kt][j] = hi;
        Bl[kt][j] = (f16)(v - (float)hi);
      }
    }
  }

  // ---- head weights / LN params into LDS (one-time) ----
  for (int idx = tid; idx < 256 * 16; idx += NTHR) {
    int k = idx >> 4, cc = idx & 15;
    w1_lds[cc][k] = W1[k * 256 + k0 + cc];
  }
  for (int idx = tid; idx < 256 * 8; idx += NTHR) {
    int k = idx >> 3, cc = idx & 7;
    w2_lds[cc][k] = W2[k * 128 + jm * 8 + cc];
  }
  lng_lds[tid] = LNG[tid];
  lnb_lds[tid] = LNB[tid];

  const int gr = tid >> 4, gk = tid & 15;
  const float bias0 = Bg[      k0 + gk];
  const float bias1 = Bg[256 + k0 + gk];
  const float bias2 = Bg[512 + k0 + gk];
  const float bias3 = Bg[768 + k0 + gk];
  const float b1reg = B1[k0 + gk];
  const float b2reg = (tid < 128) ? B2[jm * 8 + (tid & 7)] : 0.0f;
  float c_reg = 0.0f;

  // ---- init A: x(0) converted in; h region zeroed ----
  {
    const float* xp = X + (size_t)(n0 + (tid >> 4)) * 131072 + (size_t)(tid & 15) * 8;
    float4 xa = *(const float4*)xp;
    float4 xb = *(const float4*)(xp + 4);
    conv8_wr(xa, xb, &A_hi[tid >> 4][(tid & 15) * 8], &A_lo[tid >> 4][(tid & 15) * 8]);
    f16x8v z8 = {0,0,0,0,0,0,0,0};
    *(f16x8v*)&A_hi[tid >> 4][128 + (tid & 15) * 16] = z8;
    *(f16x8v*)&A_hi[tid >> 4][136 + (tid & 15) * 16] = z8;
    *(f16x8v*)&A_lo[tid >> 4][128 + (tid & 15) * 16] = z8;
    *(f16x8v*)&A_lo[tid >> 4][136 + (tid & 15) * 16] = z8;
  }
  __syncthreads();

  // stage h slice (16 rows x 256) from hbuf into A h-region as f16 hi/lo
  auto stage_h_A = [&](const float* hs) {
    float4 v0, v1, v2, v3;
    ld4_sc(hs, v0, v1, v2, v3);     // chunk c covers row (c*4 + w), cols 4l..4l+4
    conv4_wr(v0, &A_hi[w     ][128 + 4 * l], &A_lo[w     ][128 + 4 * l]);
    conv4_wr(v1, &A_hi[w + 4 ][128 + 4 * l], &A_lo[w + 4 ][128 + 4 * l]);
    conv4_wr(v2, &A_hi[w + 8 ][128 + 4 * l], &A_lo[w + 8 ][128 + 4 * l]);
    conv4_wr(v3, &A_hi[w + 12][128 + 4 * l], &A_lo[w + 12][128 + 4 * l]);
  };

  // ================= ENCODER (t = 0..1023) =================
  for (int t = 0; t < 1024; ++t) {
    // prefetch x(t+1) into registers (plain cached; consumed after fm sync)
    float4 xa, xb;
    if (t < 1023) {
      const float* xp = X + (size_t)(n0 + (tid >> 4)) * 131072
                          + (size_t)(t + 1) * 128 + (size_t)(tid & 15) * 8;
      xa = *(const float4*)xp;
      xb = *(const float4*)(xp + 4);
    }

    // ---- x-part: frags + 12 MFMAs (independent of h(t-1)) ----
    f32x4v ac0 = {0,0,0,0}, ac1 = {0,0,0,0}, ac2 = {0,0,0,0};
    {
      f16x8v xh[4], xl[4];
      const f16* pah = &A_hi[arow][krow0];
      const f16* pal = &A_lo[arow][krow0];
      #pragma unroll
      for (int kt = 0; kt < 4; ++kt) {
        xh[kt] = *(const f16x8v*)(pah + kt * 32);
        xl[kt] = *(const f16x8v*)(pal + kt * 32);
      }
      #pragma unroll
      for (int kt = 0; kt < 4; ++kt) {
        ac0 = __builtin_amdgcn_mfma_f32_16x16x32_f16(xh[kt], Bh[kt], ac0, 0, 0, 0);
        ac1 = __builtin_amdgcn_mfma_f32_16x16x32_f16(xh[kt], Bl[kt], ac1, 0, 0, 0);
        ac2 = __builtin_amdgcn_mfma_f32_16x16x32_f16(xl[kt], Bh[kt], ac2, 0, 0, 0);
      }
    }

    // ---- wait for h(t-1), burst-stage into A h-region ----
    if (t > 0) {
      wait_bar(cg, (unsigned)(WPG * t));
      stage_h_A(hbuf + (size_t)((t - 1) & 1) * 65536 + (size_t)n0 * 256 + (size_t)tid * 4);
      __syncthreads();
    }

    // ---- h-part: frags + 24 MFMAs ----
    {
      f16x8v hh[8], hl[8];
      const f16* pah = &A_hi[arow][128 + krow0];
      const f16* pal = &A_lo[arow][128 + krow0];
      #pragma unroll
      for (int kt = 0; kt < 8; ++kt) {
        hh[kt] = *(const f16x8v*)(pah + kt * 32);
        hl[kt] = *(const f16x8v*)(pal + kt * 32);
      }
      #pragma unroll
      for (int kt = 0; kt < 8; ++kt) {
        ac0 = __builtin_amdgcn_mfma_f32_16x16x32_f16(hh[kt], Bh[kt + 4], ac0, 0, 0, 0);
        ac1 = __builtin_amdgcn_mfma_f32_16x16x32_f16(hh[kt], Bl[kt + 4], ac1, 0, 0, 0);
        ac2 = __builtin_amdgcn_mfma_f32_16x16x32_f16(hl[kt], Bh[kt + 4], ac2, 0, 0, 0);
      }
    }
    #pragma unroll
    for (int q = 0; q < 4; ++q)
      fm_lds[(l >> 4) * 4 + q][w * 16 + (l & 15)] = ac0[q] + ac1[q] + ac2[q];
    __syncthreads();

    {  // gates; publish h(t) immediately (store flight overlaps x staging)
      float fi = fm_lds[gr][     gk] + bias0;
      float ff = fm_lds[gr][16 + gk] + bias1;
      float fo = fm_lds[gr][32 + gk] + bias2;
      float fg = fm_lds[gr][48 + gk] + bias3;
      float si = sigmoidf_(fi), sf = sigmoidf_(ff), so = sigmoidf_(fo);
      float tg = tanhf(fg);
      c_reg = c_reg * sf + si * tg;
      float hv = so * tanhf(c_reg);
      store_sc(hbuf + (size_t)(t & 1) * 65536 + (size_t)(n0 + gr) * 256 + k0 + gk, hv);
    }

    // write x(t+1) into A x-region (safe: all waves' x-frag reads finished
    // before the fm sync above)
    if (t < 1023)
      conv8_wr(xa, xb, &A_hi[tid >> 4][(tid & 15) * 8], &A_lo[tid >> 4][(tid & 15) * 8]);

    arrive_bar(cg);   // vmcnt(0) drain + syncthreads + atomic
  }

  // ---- stage h(1023) for the decoder ----
  wait_bar(cg, (unsigned)(WPG * 1024));
  stage_h_A(hbuf + (size_t)65536 /* buf 1 */ + (size_t)n0 * 256 + (size_t)tid * 4);
  __syncthreads();
  unsigned arr = 1024;

  // ================= DECODER (s = 0..31) =================
  for (int s = 0; s < 32; ++s) {
    const int t = 1024 + s;

    // fm = h @ Wh + b  (k-tiles 4..11 only)
    f16x8v ah[8], al[8];
    {
      const f16* pah = &A_hi[arow][128 + krow0];
      const f16* pal = &A_lo[arow][128 + krow0];
      #pragma unroll
      for (int kt = 0; kt < 8; ++kt) {
        ah[kt] = *(const f16x8v*)(pah + kt * 32);
        al[kt] = *(const f16x8v*)(pal + kt * 32);
      }
    }
    f32x4v ac0 = {0,0,0,0}, ac1 = {0,0,0,0}, ac2 = {0,0,0,0};
    #pragma unroll
    for (int kt = 0; kt < 8; ++kt) {
      ac0 = __builtin_amdgcn_mfma_f32_16x16x32_f16(ah[kt], Bh[kt + 4], ac0, 0, 0, 0);
      ac1 = __builtin_amdgcn_mfma_f32_16x16x32_f16(ah[kt], Bl[kt + 4], ac1, 0, 0, 0);
      ac2 = __builtin_amdgcn_mfma_f32_16x16x32_f16(al[kt], Bh[kt + 4], ac2, 0, 0, 0);
    }
    #pragma unroll
    for (int q = 0; q < 4; ++q)
      fm_lds[(l >> 4) * 4 + q][w * 16 + (l & 15)] = ac0[q] + ac1[q] + ac2[q];
    __syncthreads();

    {  // RAW gates (reference decoder applies no activations to i,f,o,g)
      float fi = fm_lds[gr][     gk] + bias0;
      float ff = fm_lds[gr][16 + gk] + bias1;
      float fo = fm_lds[gr][32 + gk] + bias2;
      float fg = fm_lds[gr][48 + gk] + bias3;
      c_reg = c_reg * ff + fi * fg;
      float hv = fo * tanhf(c_reg);
      store_sc(hbuf + (size_t)(t & 1) * 65536 + (size_t)(n0 + gr) * 256 + k0 + gk, hv);
    }
    arrive_bar(cg); ++arr;
    wait_bar(cg, WPG * arr);

    {  // stage h(t): f32 -> hst (for z) AND f16 -> A (for next step's fm)
      const float* hs = hbuf + (size_t)(t & 1) * 65536 + (size_t)n0 * 256 + (size_t)tid * 4;
      float4 v0, v1, v2, v3;
      ld4_sc(hs, v0, v1, v2, v3);
      *(float4*)&hst[w     ][4 * l] = v0;
      *(float4*)&hst[w + 4 ][4 * l] = v1;
      *(float4*)&hst[w + 8 ][4 * l] = v2;
      *(float4*)&hst[w + 12][4 * l] = v3;
      conv4_wr(v0, &A_hi[w     ][128 + 4 * l], &A_lo[w     ][128 + 4 * l]);
      conv4_wr(v1, &A_hi[w + 4 ][128 + 4 * l], &A_lo[w + 4 ][128 + 4 * l]);
      conv4_wr(v2, &A_hi[w + 8 ][128 + 4 * l], &A_lo[w + 8 ][128 + 4 * l]);
      conv4_wr(v3, &A_hi[w + 12][128 + 4 * l], &A_lo[w + 12][128 + 4 * l]);
    }
    __syncthreads();

    {  // z[gr][k0+gk] = h(t)[gr] . W1[:,k0+gk] + b1
      float za = b1reg;
      const float* hr = &hst[gr][0];
      const float* wr = &w1_lds[gk][0];
      #pragma unroll 4
      for (int kc = 0; kc < 64; ++kc) {
        float4 h4 = *(const float4*)(hr + kc * 4);
        float4 w4 = *(const float4*)(wr + kc * 4);
        za = fmaf(h4.x, w4.x, fmaf(h4.y, w4.y, fmaf(h4.z, w4.z, fmaf(h4.w, w4.w, za))));
      }
      store_sc(zbuf + (size_t)(n0 + gr) * 256 + k0 + gk, za);
    }
    arrive_bar(cg); ++arr;
    wait_bar(cg, WPG * arr);

    {  // stage z -> hst
      const float* zs = zbuf + (size_t)n0 * 256 + (size_t)tid * 4;
      float4 v0, v1, v2, v3;
      ld4_sc(zs, v0, v1, v2, v3);
      *(float4*)&hst[w     ][4 * l] = v0;
      *(float4*)&hst[w + 4 ][4 * l] = v1;
      *(float4*)&hst[w + 8 ][4 * l] = v2;
      *(float4*)&hst[w + 12][4 * l] = v3;
    }
    __syncthreads();

    {  // LayerNorm stats
      const float* zr = &hst[gr][0];
      float s1 = 0.f, s2 = 0.f;
      #pragma unroll
      for (int u = 0; u < 16; ++u) { float v = zr[gk * 16 + u]; s1 += v; s2 += v * v; }
      #pragma unroll
      for (int d = 1; d < 16; d <<= 1) { s1 += __shfl_xor(s1, d); s2 += __shfl_xor(s2, d); }
      float mu = s1 * (1.0f / 256.0f);
      float var = s2 * (1.0f / 256.0f) - mu * mu;
      float rstd = rsqrtf(var + 1e-5f);
      if (gk == 0) { ln_mu[gr] = mu; ln_rs[gr] = rstd; }
    }
    __syncthreads();

    #pragma unroll
    for (int rep = 0; rep < 4; ++rep) {  // normalize + affine + relu in place
      int f = tid + 256 * rep, r = f >> 6, kq = f & 63;
      float mu = ln_mu[r], rs = ln_rs[r];
      float4 v = *(float4*)&hst[r][kq * 4];
      int cb = kq * 4;
      v.x = fmaxf(fmaf((v.x - mu) * rs, lng_lds[cb    ], lnb_lds[cb    ]), 0.f);
      v.y = fmaxf(fmaf((v.y - mu) * rs, lng_lds[cb + 1], lnb_lds[cb + 1]), 0.f);
      v.z = fmaxf(fmaf((v.z - mu) * rs, lng_lds[cb + 2], lnb_lds[cb + 2]), 0.f);
      v.w = fmaxf(fmaf((v.w - mu) * rs, lng_lds[cb + 3], lnb_lds[cb + 3]), 0.f);
      *(float4*)&hst[r][kq * 4] = v;
    }
    __syncthreads();

    if (tid < 128) {  // y[r][jm*8+yc] = relu(zn)[r] . W2[:,jm*8+yc] + b2
      int r = tid >> 3, yc = tid & 7;
      float ya = b2reg;
      const float* zr = &hst[r][0];
      const float* wr = &w2_lds[yc][0];
      #pragma unroll 4
      for (int kc = 0; kc < 64; ++kc) {
        float4 z4 = *(const float4*)(zr + kc * 4);
        float4 w4 = *(const float4*)(wr + kc * 4);
        ya = fmaf(z4.x, w4.x, fmaf(z4.y, w4.y, fmaf(z4.z, w4.z, fmaf(z4.w, w4.w, ya))));
      }
      Y[(size_t)(n0 + r) * 4096 + (size_t)s * 128 + jm * 8 + yc] = ya;
    }
    // hst reuse next iteration is safe: two barrier waits intervene.
  }
}

extern "C" void kernel_launch(void* const* d_in, const int* in_sizes, int n_in,
                              void* d_out, int out_size, void* d_ws, size_t ws_size,
                              hipStream_t stream) {
  const float* X   = (const float*)d_in[0];
  const float* Wx  = (const float*)d_in[1];
  const float* Wh  = (const float*)d_in[2];
  const float* b   = (const float*)d_in[3];
  const float* W1  = (const float*)d_in[4];
  const float* b1  = (const float*)d_in[5];
  const float* lng = (const float*)d_in[6];
  const float* lnb = (const float*)d_in[7];
  const float* W2  = (const float*)d_in[8];
  const float* b2  = (const float*)d_in[9];
  float* Y = (float*)d_out;

  unsigned* cnt = (unsigned*)d_ws;
  float* hbuf = (float*)((char*)d_ws + 2048);
  float* zbuf = hbuf + 2 * 256 * 256;
  (void)in_sizes; (void)n_in; (void)out_size; (void)ws_size;

  hipMemsetAsync(d_ws, 0, 2048, stream);
  hipLaunchKernelGGL(lstm_k, dim3(256), dim3(NTHR), 0, stream,
                     X, Wx, Wh, b, W1, b1, lng, lnb, W2, b2, Y, cnt, hbuf, zbuf);
}